// Round 2
// baseline (588.315 us; speedup 1.0000x reference)
//
#include <hip/hip_runtime.h>
#include <hip/hip_bf16.h>
#include <stdint.h>

// BitLinear: out = LayerNorm(x) @ sign(W - mean(W))^T * mean|W - mean(W)|
// M=8192 (B*S), K=4096 (D_in), N=4096 (D_out). fp32 in/out, bf16 MFMA GEMM.
//
// GEMM: 256x256 tile, BK=64, 8 waves (2Mx4N), 4-phase/tile schedule with
// intra-tile ds_read read-ahead (reads for phase p+1 issued before phase p's
// MFMA cluster -> LDS delivery hides under MFMA), ONE barrier per phase,
// T-loop unrolled x2 (compile-time LDS buffers), counted vmcnt (never 0 in
// loop), LDS XOR-swizzle (T2, conflict-free), setprio (T5), XCD swizzle (T1).

typedef __bf16 bf16x8 __attribute__((ext_vector_type(8)));
typedef float f32x4 __attribute__((ext_vector_type(4)));

#define LDS_BUF 65536  // one K-tile: A 32KB + B 32KB

// ---------- helpers ----------

__device__ __forceinline__ void gl_lds16(const void* g, void* l) {
  // async global->LDS, 16B/lane; LDS dest is wave-uniform base + lane*16
  __builtin_amdgcn_global_load_lds(
      (const __attribute__((address_space(1))) void*)g,
      (__attribute__((address_space(3))) void*)l,
      16, 0, 0);
}

__device__ __forceinline__ unsigned short f2bf_rne(float f) {
  unsigned int u = __float_as_uint(f);
  unsigned int r = (u + 0x7FFFu + ((u >> 16) & 1u)) >> 16;
  return (unsigned short)r;
}

__device__ __forceinline__ float wave_red(float v) {
#pragma unroll
  for (int o = 32; o > 0; o >>= 1) v += __shfl_down(v, o, 64);
  return v;
}

// valid on threadIdx.x==0 only
__device__ __forceinline__ float block_red(float v) {
  __shared__ float tmp[4];
  const int wave = threadIdx.x >> 6, lane = threadIdx.x & 63;
  v = wave_red(v);
  if (lane == 0) tmp[wave] = v;
  __syncthreads();
  float r = 0.f;
  if (threadIdx.x == 0) r = tmp[0] + tmp[1] + tmp[2] + tmp[3];
  return r;
}

// ---------- preprocessing kernels (unchanged, verified) ----------

__global__ void zero_kernel(float* p) {
  if (threadIdx.x < 8) p[threadIdx.x] = 0.f;
}

__global__ __launch_bounds__(256) void wsum_kernel(const float* __restrict__ w,
                                                   float* __restrict__ scal, int n4) {
  int idx = blockIdx.x * 256 + threadIdx.x;
  int stride = gridDim.x * 256;
  const float4* w4 = (const float4*)w;
  float s = 0.f;
  for (int i = idx; i < n4; i += stride) {
    float4 a = w4[i];
    s += a.x + a.y + a.z + a.w;
  }
  float tot = block_red(s);
  if (threadIdx.x == 0) atomicAdd(&scal[0], tot);
}

__global__ __launch_bounds__(256) void wbin_kernel(const float* __restrict__ w,
                                                   float* __restrict__ scal,
                                                   unsigned short* __restrict__ wb,
                                                   int n4, float inv_n) {
  const float mean = scal[0] * inv_n;
  int idx = blockIdx.x * 256 + threadIdx.x;
  int stride = gridDim.x * 256;
  const float4* w4 = (const float4*)w;
  ushort4* wb4 = (ushort4*)wb;
  float sa = 0.f;
  for (int i = idx; i < n4; i += stride) {
    float4 a = w4[i];
    float dx = a.x - mean, dy = a.y - mean, dz = a.z - mean, dw = a.w - mean;
    sa += fabsf(dx) + fabsf(dy) + fabsf(dz) + fabsf(dw);
    ushort4 o;
    o.x = dx > 0.f ? 0x3F80u : (dx < 0.f ? 0xBF80u : 0u);
    o.y = dy > 0.f ? 0x3F80u : (dy < 0.f ? 0xBF80u : 0u);
    o.z = dz > 0.f ? 0x3F80u : (dz < 0.f ? 0xBF80u : 0u);
    o.w = dw > 0.f ? 0x3F80u : (dw < 0.f ? 0xBF80u : 0u);
    wb4[i] = o;
  }
  float tot = block_red(sa);
  if (threadIdx.x == 0) atomicAdd(&scal[1], tot);
}

__global__ __launch_bounds__(256) void ln_kernel(const float* __restrict__ x,
                                                 __bf16* __restrict__ xn) {
  const int row = blockIdx.x;
  const float4* xr = (const float4*)(x + (size_t)row * 4096);
  const int tid = threadIdx.x;
  float4 v[4];
  float s = 0.f, ss = 0.f;
#pragma unroll
  for (int t = 0; t < 4; t++) {
    float4 a = xr[t * 256 + tid];
    v[t] = a;
    s += a.x + a.y + a.z + a.w;
    ss += a.x * a.x + a.y * a.y + a.z * a.z + a.w * a.w;
  }
#pragma unroll
  for (int o = 32; o > 0; o >>= 1) {
    s += __shfl_down(s, o, 64);
    ss += __shfl_down(ss, o, 64);
  }
  __shared__ float rs[8];
  const int wave = tid >> 6, lane = tid & 63;
  if (lane == 0) { rs[wave] = s; rs[4 + wave] = ss; }
  __syncthreads();
  s = rs[0] + rs[1] + rs[2] + rs[3];
  ss = rs[4] + rs[5] + rs[6] + rs[7];
  const float mu = s * (1.0f / 4096.0f);
  const float var = ss * (1.0f / 4096.0f) - mu * mu;  // jnp.var: population
  const float rstd = rsqrtf(var + 1e-5f);
  ushort4* xw = (ushort4*)((unsigned short*)xn + (size_t)row * 4096);
#pragma unroll
  for (int t = 0; t < 4; t++) {
    float4 a = v[t];
    ushort4 o;
    o.x = f2bf_rne((a.x - mu) * rstd);
    o.y = f2bf_rne((a.y - mu) * rstd);
    o.z = f2bf_rne((a.z - mu) * rstd);
    o.w = f2bf_rne((a.w - mu) * rstd);
    xw[t * 256 + tid] = o;
  }
}

// ---------- GEMM: 256x256 tile, BK=64, read-ahead pipelined ----------
//
// LDS layout / swizzle / staging math: identical to the verified r1 kernel.
// Phase schedule (one barrier per phase; slot ledger re-verified):
//   p1: reads(A00,B0h) serial | stage bo{A11',B10',B11'} kt1 | readahead A01
//       | MFMA acc[0..3] | bar
//   p2: stage bc{A00''} kt2 | readahead A10,B1h | MFMA acc[4..7] (A01 x B0h) | bar
//   p3: stage bc{A01'',B00''} | readahead A11 | MFMA acc[0..3] (A10 x B1h) | bar
//   p4: stage bc{A10'',B01''} | vmcnt(5) | MFMA acc[4..7] (A11 x B1h) | bar
// Hazard edges: slot X staged at phase q needs all-waves lgkm(X) at <= q-1:
//   A00 r:p1/s:p2, A01 r:p2/s:p3, B0h r:p1/s:p3+p4, A10 r:p3/s:p4,
//   B1h+A11 r:p3,p4 / re-staged next-tile p1 (after p4 exit bar). All hold.
// vmcnt(5) after p4 stages, before exit bar: all 8 blocks of tile T+1 landed
// before any wave issues tile T+1 reads (cross-tile reads stay AFTER the
// barrier -- each wave's vmcnt only covers its own loads; the barrier makes
// the guarantee mutual, which is why p1 has no read-ahead).

__global__ __launch_bounds__(512, 2) void gemm_kernel(
    const __bf16* __restrict__ A, const __bf16* __restrict__ Bm,
    float* __restrict__ C, const float* __restrict__ scal,
    float beta_scale, int M, int N, int K) {
  extern __shared__ __align__(16) char sm[];

  const int tid = threadIdx.x;
  const int wave = tid >> 6, lane = tid & 63;
  const int wm = wave >> 2, wn = wave & 3;      // 2 M-waves x 4 N-waves
  const int fr = lane & 15, hi4 = lane >> 4;

  // T1: XCD swizzle (bijective: nwg=512 % 8 == 0), col-major tile map
  const int nwg = gridDim.x;
  const int swz = (blockIdx.x & 7) * (nwg >> 3) + (blockIdx.x >> 3);
  const int TM = M >> 8;
  const int tm = swz % TM, tn = swz / TM;
  const int rowBase = tm << 8, colBase = tn << 8;

  // staging: linear LDS dest byte d = tid*16; source holds logical swz(d)
  const int s = (tid & 7) ^ ((tid >> 3) & 7);
  const int rb = ((tid >> 2) & ~1) | (s >> 2);   // row-in-block 0..127
  const int colOff = (s & 3) << 3;               // K elems 0/8/16/24
  const __bf16* srcA0 = A + (size_t)(rowBase + (rb & 63) + ((rb >> 6) << 7)) * K + colOff;
  const __bf16* srcB0 = Bm + (size_t)(colBase + rb) * K + colOff;
  const int waveOff = wave << 10;

  // fragment read bases (pre-swizzled)
  int abase = (wm << 12) + (fr << 6) + (hi4 << 4);
  abase ^= ((abase >> 7) & 7) << 4;
  int bbase = ((wn >> 1) << 13) + ((wn & 1) << 12) + (fr << 6) + (hi4 << 4);
  bbase ^= ((bbase >> 7) & 7) << 4;

  char* const buf0 = sm;
  char* const buf1 = sm + LDS_BUF;

  auto stA = [&](char* buf, int k, int qm, int kt) {
    gl_lds16(srcA0 + (size_t)(qm << 6) * K + (kt + (k << 5)),
             buf + (k << 14) + (qm << 13) + waveOff);
  };
  auto stB = [&](char* buf, int k, int half, int kt) {
    gl_lds16(srcB0 + (size_t)(half << 7) * K + (kt + (k << 5)),
             buf + 32768 + (k << 14) + (half << 13) + waveOff);
  };

  f32x4 acc[8][4];
#pragma unroll
  for (int i = 0; i < 8; i++)
#pragma unroll
    for (int j = 0; j < 4; j++) acc[i][j] = (f32x4){0.f, 0.f, 0.f, 0.f};

  const int NT = K >> 6;  // 64

  // prologue: tile0 complete (8 blocks) + tile1's pre-p1 set (5 blocks)
  stA(buf0, 0, 0, 0); stA(buf0, 0, 1, 0); stB(buf0, 0, 0, 0); stB(buf0, 0, 1, 0);
  stA(buf0, 1, 0, 0); stA(buf0, 1, 1, 0); stB(buf0, 1, 0, 0); stB(buf0, 1, 1, 0);
  stA(buf1, 0, 0, 64); stA(buf1, 0, 1, 64); stB(buf1, 0, 0, 64);
  stA(buf1, 1, 0, 64); stB(buf1, 0, 1, 64);
  asm volatile("s_waitcnt vmcnt(5)" ::: "memory");  // tile0 landed, 5 in flight
  asm volatile("s_barrier" ::: "memory");

  auto tile = [&](char* bc, char* bo, int T) {
    const int kt1 = ((T + 1 < NT) ? T + 1 : NT - 1) << 6;
    const int kt2 = ((T + 2 < NT) ? T + 2 : NT - 1) << 6;
    bf16x8 aA[4], aB[4], bA[4], bB[4];

    // ---- phase 1: qm=0,k=0 (serial reads at tile boundary) ----
#pragma unroll
    for (int i = 0; i < 4; i++) aA[i] = *(const bf16x8*)(bc + abase + (i << 10));
#pragma unroll
    for (int j = 0; j < 4; j++) bA[j] = *(const bf16x8*)(bc + 32768 + bbase + (j << 10));
    stA(bo, 1, 1, kt1); stB(bo, 1, 0, kt1); stB(bo, 1, 1, kt1);
    // read-ahead for p2 (delivery hides under p1 MFMA)
#pragma unroll
    for (int i = 0; i < 4; i++) aB[i] = *(const bf16x8*)(bc + (1 << 13) + abase + (i << 10));
    __builtin_amdgcn_sched_barrier(0);
    __builtin_amdgcn_s_setprio(1);
#pragma unroll
    for (int i = 0; i < 4; i++)
#pragma unroll
      for (int j = 0; j < 4; j++)
        acc[i][j] = __builtin_amdgcn_mfma_f32_16x16x32_bf16(aA[i], bA[j], acc[i][j], 0, 0, 0);
    __builtin_amdgcn_s_setprio(0);
    __builtin_amdgcn_sched_barrier(0);
    asm volatile("s_barrier" ::: "memory");

    // ---- phase 2: qm=1,k=0 ----
    stA(bc, 0, 0, kt2);
    // read-ahead for p3
#pragma unroll
    for (int i = 0; i < 4; i++) aA[i] = *(const bf16x8*)(bc + (1 << 14) + abase + (i << 10));
#pragma unroll
    for (int j = 0; j < 4; j++) bB[j] = *(const bf16x8*)(bc + 32768 + (1 << 14) + bbase + (j << 10));
    __builtin_amdgcn_sched_barrier(0);
    __builtin_amdgcn_s_setprio(1);
#pragma unroll
    for (int i = 0; i < 4; i++)
#pragma unroll
      for (int j = 0; j < 4; j++)
        acc[4 + i][j] = __builtin_amdgcn_mfma_f32_16x16x32_bf16(aB[i], bA[j], acc[4 + i][j], 0, 0, 0);
    __builtin_amdgcn_s_setprio(0);
    __builtin_amdgcn_sched_barrier(0);
    asm volatile("s_barrier" ::: "memory");

    // ---- phase 3: qm=0,k=1 ----
    stA(bc, 0, 1, kt2); stB(bc, 0, 0, kt2);
    // read-ahead for p4
#pragma unroll
    for (int i = 0; i < 4; i++) aB[i] = *(const bf16x8*)(bc + (1 << 14) + (1 << 13) + abase + (i << 10));
    __builtin_amdgcn_sched_barrier(0);
    __builtin_amdgcn_s_setprio(1);
#pragma unroll
    for (int i = 0; i < 4; i++)
#pragma unroll
      for (int j = 0; j < 4; j++)
        acc[i][j] = __builtin_amdgcn_mfma_f32_16x16x32_bf16(aA[i], bB[j], acc[i][j], 0, 0, 0);
    __builtin_amdgcn_s_setprio(0);
    __builtin_amdgcn_sched_barrier(0);
    asm volatile("s_barrier" ::: "memory");

    // ---- phase 4: qm=1,k=1 ----
    stA(bc, 1, 0, kt2); stB(bc, 0, 1, kt2);
    asm volatile("s_waitcnt vmcnt(5)" ::: "memory");  // tile T+1 fully landed
    __builtin_amdgcn_sched_barrier(0);
    __builtin_amdgcn_s_setprio(1);
#pragma unroll
    for (int i = 0; i < 4; i++)
#pragma unroll
      for (int j = 0; j < 4; j++)
        acc[4 + i][j] = __builtin_amdgcn_mfma_f32_16x16x32_bf16(aB[i], bB[j], acc[4 + i][j], 0, 0, 0);
    __builtin_amdgcn_s_setprio(0);
    __builtin_amdgcn_sched_barrier(0);
    asm volatile("s_barrier" ::: "memory");
  };

  for (int T = 0; T < NT; T += 2) {
    tile(buf0, buf1, T);
    tile(buf1, buf0, T + 1);
  }

  // drain tail prefetches
  asm volatile("s_waitcnt vmcnt(0)" ::: "memory");

  // epilogue: C/D layout col=lane&15, row=(lane>>4)*4+reg [m89/m91 verified]
  const float beta = scal[1] * beta_scale;
  const int orow0 = rowBase + (wm << 7) + (hi4 << 2);
  const int ocol = colBase + (wn << 6) + fr;
#pragma unroll
  for (int mf = 0; mf < 8; mf++)
#pragma unroll
    for (int j = 0; j < 4; j++)
#pragma unroll
      for (int r = 0; r < 4; r++)
        C[(size_t)(orow0 + mf * 16 + r) * N + (ocol + j * 16)] = acc[mf][j][r] * beta;
}

// ---------- launch ----------

extern "C" void kernel_launch(void* const* d_in, const int* in_sizes, int n_in,
                              void* d_out, int out_size, void* d_ws, size_t ws_size,
                              hipStream_t stream) {
  const float* x = (const float*)d_in[0];   // [4,2048,4096] fp32
  const float* w = (const float*)d_in[1];   // [4096,4096] fp32
  float* out = (float*)d_out;               // [4,2048,4096] fp32

  const int K = 4096;
  const int M = in_sizes[0] / K;  // 8192
  const int N = in_sizes[1] / K;  // 4096
  const int nw = N * K;           // 16777216
  const float inv_nw = 1.0f / (float)nw;

  char* ws = (char*)d_ws;
  float* scal = (float*)ws;                                  // [0]=sum(W), [1]=sum|W-mean|
  __bf16* wbin = (__bf16*)(ws + 256);                        // N*K bf16 = 32 MB
  __bf16* xn = (__bf16*)(ws + 256 + (size_t)nw * 2);         // M*K bf16 = 64 MB

  static int attr_done = 0;
  if (!attr_done) {
    hipFuncSetAttribute((const void*)gemm_kernel,
                        hipFuncAttributeMaxDynamicSharedMemorySize, 2 * LDS_BUF);
    attr_done = 1;
  }

  zero_kernel<<<1, 64, 0, stream>>>(scal);
  wsum_kernel<<<1024, 256, 0, stream>>>(w, scal, nw / 4);
  wbin_kernel<<<1024, 256, 0, stream>>>(w, scal, (unsigned short*)wbin, nw / 4, inv_nw);
  ln_kernel<<<M, 256, 0, stream>>>(x, xn);
  const int nwg = (M >> 8) * (N >> 8);  // 32*16 = 512
  gemm_kernel<<<dim3(nwg), 512, 2 * LDS_BUF, stream>>>(xn, wbin, out, scal, inv_nw, M, N, K);
}

// Round 3
// 570.882 us; speedup vs baseline: 1.0305x; 1.0305x over previous
//
#include <hip/hip_runtime.h>
#include <hip/hip_bf16.h>
#include <stdint.h>

// BitLinear: out = LayerNorm(x) @ sign(W - mean(W))^T * mean|W - mean(W)|
// M=8192 (B*S), K=4096 (D_in), N=4096 (D_out). fp32 in/out, bf16 MFMA GEMM.
//
// GEMM: 256x256 tile, BK=64, 8 waves (2Mx4N), m201 8-phase body (2 barriers
// per phase, lgkm(0) after the pre-MFMA barrier), PLUS post-MFMA read-ahead:
// phase p+1's ds_reads issue after phase p's MFMA cluster (double-buffered
// fragment regs), so LDS delivery hides under MFMA + barrier skew.
// Ledger identical to the verified r1 kernel (same barriers/stages/vmcnt).

typedef __bf16 bf16x8 __attribute__((ext_vector_type(8)));
typedef float f32x4 __attribute__((ext_vector_type(4)));

#define LDS_BUF 65536  // one K-tile: A 32KB + B 32KB

// ---------- helpers ----------

__device__ __forceinline__ void gl_lds16(const void* g, void* l) {
  // async global->LDS, 16B/lane; LDS dest is wave-uniform base + lane*16
  __builtin_amdgcn_global_load_lds(
      (const __attribute__((address_space(1))) void*)g,
      (__attribute__((address_space(3))) void*)l,
      16, 0, 0);
}

__device__ __forceinline__ unsigned short f2bf_rne(float f) {
  unsigned int u = __float_as_uint(f);
  unsigned int r = (u + 0x7FFFu + ((u >> 16) & 1u)) >> 16;
  return (unsigned short)r;
}

__device__ __forceinline__ float wave_red(float v) {
#pragma unroll
  for (int o = 32; o > 0; o >>= 1) v += __shfl_down(v, o, 64);
  return v;
}

// valid on threadIdx.x==0 only
__device__ __forceinline__ float block_red(float v) {
  __shared__ float tmp[4];
  const int wave = threadIdx.x >> 6, lane = threadIdx.x & 63;
  v = wave_red(v);
  if (lane == 0) tmp[wave] = v;
  __syncthreads();
  float r = 0.f;
  if (threadIdx.x == 0) r = tmp[0] + tmp[1] + tmp[2] + tmp[3];
  return r;
}

// ---------- preprocessing kernels (unchanged, verified) ----------

__global__ void zero_kernel(float* p) {
  if (threadIdx.x < 8) p[threadIdx.x] = 0.f;
}

__global__ __launch_bounds__(256) void wsum_kernel(const float* __restrict__ w,
                                                   float* __restrict__ scal, int n4) {
  int idx = blockIdx.x * 256 + threadIdx.x;
  int stride = gridDim.x * 256;
  const float4* w4 = (const float4*)w;
  float s = 0.f;
  for (int i = idx; i < n4; i += stride) {
    float4 a = w4[i];
    s += a.x + a.y + a.z + a.w;
  }
  float tot = block_red(s);
  if (threadIdx.x == 0) atomicAdd(&scal[0], tot);
}

__global__ __launch_bounds__(256) void wbin_kernel(const float* __restrict__ w,
                                                   float* __restrict__ scal,
                                                   unsigned short* __restrict__ wb,
                                                   int n4, float inv_n) {
  const float mean = scal[0] * inv_n;
  int idx = blockIdx.x * 256 + threadIdx.x;
  int stride = gridDim.x * 256;
  const float4* w4 = (const float4*)w;
  ushort4* wb4 = (ushort4*)wb;
  float sa = 0.f;
  for (int i = idx; i < n4; i += stride) {
    float4 a = w4[i];
    float dx = a.x - mean, dy = a.y - mean, dz = a.z - mean, dw = a.w - mean;
    sa += fabsf(dx) + fabsf(dy) + fabsf(dz) + fabsf(dw);
    ushort4 o;
    o.x = dx > 0.f ? 0x3F80u : (dx < 0.f ? 0xBF80u : 0u);
    o.y = dy > 0.f ? 0x3F80u : (dy < 0.f ? 0xBF80u : 0u);
    o.z = dz > 0.f ? 0x3F80u : (dz < 0.f ? 0xBF80u : 0u);
    o.w = dw > 0.f ? 0x3F80u : (dw < 0.f ? 0xBF80u : 0u);
    wb4[i] = o;
  }
  float tot = block_red(sa);
  if (threadIdx.x == 0) atomicAdd(&scal[1], tot);
}

__global__ __launch_bounds__(256) void ln_kernel(const float* __restrict__ x,
                                                 __bf16* __restrict__ xn) {
  const int row = blockIdx.x;
  const float4* xr = (const float4*)(x + (size_t)row * 4096);
  const int tid = threadIdx.x;
  float4 v[4];
  float s = 0.f, ss = 0.f;
#pragma unroll
  for (int t = 0; t < 4; t++) {
    float4 a = xr[t * 256 + tid];
    v[t] = a;
    s += a.x + a.y + a.z + a.w;
    ss += a.x * a.x + a.y * a.y + a.z * a.z + a.w * a.w;
  }
#pragma unroll
  for (int o = 32; o > 0; o >>= 1) {
    s += __shfl_down(s, o, 64);
    ss += __shfl_down(ss, o, 64);
  }
  __shared__ float rs[8];
  const int wave = tid >> 6, lane = tid & 63;
  if (lane == 0) { rs[wave] = s; rs[4 + wave] = ss; }
  __syncthreads();
  s = rs[0] + rs[1] + rs[2] + rs[3];
  ss = rs[4] + rs[5] + rs[6] + rs[7];
  const float mu = s * (1.0f / 4096.0f);
  const float var = ss * (1.0f / 4096.0f) - mu * mu;  // jnp.var: population
  const float rstd = rsqrtf(var + 1e-5f);
  ushort4* xw = (ushort4*)((unsigned short*)xn + (size_t)row * 4096);
#pragma unroll
  for (int t = 0; t < 4; t++) {
    float4 a = v[t];
    ushort4 o;
    o.x = f2bf_rne((a.x - mu) * rstd);
    o.y = f2bf_rne((a.y - mu) * rstd);
    o.z = f2bf_rne((a.z - mu) * rstd);
    o.w = f2bf_rne((a.w - mu) * rstd);
    xw[t * 256 + tid] = o;
  }
}

// ---------- GEMM: 256x256 tile, BK=64, post-MFMA read-ahead ----------
//
// LDS per buffer (64 KB): A blocks (k,qm) at ((k*2+qm)<<13), each 8 KB =
//   {rows [qm*64,qm*64+64) for wm=0 at +0, same rows +128 for wm=1 at +4096},
//   row = 64 B. B blocks (k,half) at 32768+((k*2+half)<<13).
// Swizzle (involution within 8-KB block): byte ^= ((byte>>7)&7)<<4.
//   gl_lds dest LINEAR; inverse swizzle on per-lane GLOBAL source (rule #21).
//
// Phase structure (2 barriers/phase, identical barrier/stage/vmcnt ledger
// to the verified 289us r1 kernel; ONLY reads moved):
//   w1(p): stages(p)            | Bpre(p)
//   w2(p): lgkm(0); setprio(1); 16 MFMA; setprio(0); reads(p+1) | Bpost(p)
// reads(p+1) drain at w2(p+1)'s lgkm(0) -- same drain point relative to
// every barrier as r1, so all stage-slot hazard edges are unchanged:
//   A00 r:p1/s:p2, A01 r:p2/s:p3, B0h r:p1/s:p3+p4, A10 r:p3/s:p4,
//   B1h+A11 r:p3,p4 / staged next-tile p1 (after p4 exit barrier).
// vmcnt(5) in w1(p4): 13 outstanding worst-case -> drains all 8 of tile T+1,
// leaves exactly T+2's 5 partial set. p1 reads stay serial (cross-tile
// visibility requires vmcnt(5)+barrier before any wave touches the buffer).

__global__ __launch_bounds__(512, 2) void gemm_kernel(
    const __bf16* __restrict__ A, const __bf16* __restrict__ Bm,
    float* __restrict__ C, const float* __restrict__ scal,
    float beta_scale, int M, int N, int K) {
  extern __shared__ __align__(16) char sm[];

  const int tid = threadIdx.x;
  const int wave = tid >> 6, lane = tid & 63;
  const int wm = wave >> 2, wn = wave & 3;      // 2 M-waves x 4 N-waves
  const int fr = lane & 15, hi4 = lane >> 4;

  // T1: XCD swizzle (bijective: nwg=512 % 8 == 0), col-major tile map
  const int nwg = gridDim.x;
  const int swz = (blockIdx.x & 7) * (nwg >> 3) + (blockIdx.x >> 3);
  const int TM = M >> 8;
  const int tm = swz % TM, tn = swz / TM;
  const int rowBase = tm << 8, colBase = tn << 8;

  // staging: linear LDS dest byte d = tid*16; source holds logical swz(d)
  const int s = (tid & 7) ^ ((tid >> 3) & 7);
  const int rb = ((tid >> 2) & ~1) | (s >> 2);   // row-in-block 0..127
  const int colOff = (s & 3) << 3;               // K elems 0/8/16/24
  const __bf16* srcA0 = A + (size_t)(rowBase + (rb & 63) + ((rb >> 6) << 7)) * K + colOff;
  const __bf16* srcB0 = Bm + (size_t)(colBase + rb) * K + colOff;
  const int waveOff = wave << 10;

  // fragment read bases (pre-swizzled)
  int abase = (wm << 12) + (fr << 6) + (hi4 << 4);
  abase ^= ((abase >> 7) & 7) << 4;
  int bbase = ((wn >> 1) << 13) + ((wn & 1) << 12) + (fr << 6) + (hi4 << 4);
  bbase ^= ((bbase >> 7) & 7) << 4;

  char* const buf0 = sm;
  char* const buf1 = sm + LDS_BUF;

  auto stA = [&](char* buf, int k, int qm, int kt) {
    gl_lds16(srcA0 + (size_t)(qm << 6) * K + (kt + (k << 5)),
             buf + (k << 14) + (qm << 13) + waveOff);
  };
  auto stB = [&](char* buf, int k, int half, int kt) {
    gl_lds16(srcB0 + (size_t)(half << 7) * K + (kt + (k << 5)),
             buf + 32768 + (k << 14) + (half << 13) + waveOff);
  };

  f32x4 acc[8][4];
#pragma unroll
  for (int i = 0; i < 8; i++)
#pragma unroll
    for (int j = 0; j < 4; j++) acc[i][j] = (f32x4){0.f, 0.f, 0.f, 0.f};

  const int NT = K >> 6;  // 64

  // prologue: tile0 complete (8 blocks) + tile1's pre-p1 set (5 blocks)
  stA(buf0, 0, 0, 0); stA(buf0, 0, 1, 0); stB(buf0, 0, 0, 0); stB(buf0, 0, 1, 0);
  stA(buf0, 1, 0, 0); stA(buf0, 1, 1, 0); stB(buf0, 1, 0, 0); stB(buf0, 1, 1, 0);
  stA(buf1, 0, 0, 64); stA(buf1, 0, 1, 64); stB(buf1, 0, 0, 64);
  stA(buf1, 1, 0, 64); stB(buf1, 0, 1, 64);
  asm volatile("s_waitcnt vmcnt(5)" ::: "memory");  // tile0 landed, 5 in flight
  asm volatile("s_barrier" ::: "memory");

  for (int T = 0; T < NT; ++T) {
    char* const bc = (T & 1) ? buf1 : buf0;
    char* const bo = (T & 1) ? buf0 : buf1;
    const int kt1 = ((T + 1 < NT) ? T + 1 : NT - 1) << 6;
    const int kt2 = ((T + 2 < NT) ? T + 2 : NT - 1) << 6;

    bf16x8 a0[4], a1[4], b0[4], b1[4];

    // ==== phase 1: qm=0,k=0 ====
    // w1: serial reads (tile boundary) + bo stages
#pragma unroll
    for (int i = 0; i < 4; i++) a0[i] = *(const bf16x8*)(bc + abase + (i << 10));
#pragma unroll
    for (int j = 0; j < 4; j++) b0[j] = *(const bf16x8*)(bc + 32768 + bbase + (j << 10));
    stA(bo, 1, 1, kt1); stB(bo, 1, 0, kt1); stB(bo, 1, 1, kt1);
    asm volatile("s_barrier" ::: "memory");
    // w2
    asm volatile("s_waitcnt lgkmcnt(0)" ::: "memory");
    __builtin_amdgcn_s_setprio(1);
#pragma unroll
    for (int i = 0; i < 4; i++)
#pragma unroll
      for (int j = 0; j < 4; j++)
        acc[i][j] = __builtin_amdgcn_mfma_f32_16x16x32_bf16(a0[i], b0[j], acc[i][j], 0, 0, 0);
    __builtin_amdgcn_s_setprio(0);
    // read-ahead p2: A01 (delivery hides under MFMA + barriers)
#pragma unroll
    for (int i = 0; i < 4; i++) a1[i] = *(const bf16x8*)(bc + (1 << 13) + abase + (i << 10));
    asm volatile("s_barrier" ::: "memory");

    // ==== phase 2: qm=1,k=0 (b0 reused) ====
    stA(bc, 0, 0, kt2);
    asm volatile("s_barrier" ::: "memory");
    asm volatile("s_waitcnt lgkmcnt(0)" ::: "memory");
    __builtin_amdgcn_s_setprio(1);
#pragma unroll
    for (int i = 0; i < 4; i++)
#pragma unroll
      for (int j = 0; j < 4; j++)
        acc[4 + i][j] = __builtin_amdgcn_mfma_f32_16x16x32_bf16(a1[i], b0[j], acc[4 + i][j], 0, 0, 0);
    __builtin_amdgcn_s_setprio(0);
    // read-ahead p3: A10 + B1h
#pragma unroll
    for (int i = 0; i < 4; i++) a0[i] = *(const bf16x8*)(bc + (1 << 14) + abase + (i << 10));
#pragma unroll
    for (int j = 0; j < 4; j++) b1[j] = *(const bf16x8*)(bc + 32768 + (1 << 14) + bbase + (j << 10));
    asm volatile("s_barrier" ::: "memory");

    // ==== phase 3: qm=0,k=1 ====
    stA(bc, 0, 1, kt2); stB(bc, 0, 0, kt2);
    asm volatile("s_barrier" ::: "memory");
    asm volatile("s_waitcnt lgkmcnt(0)" ::: "memory");
    __builtin_amdgcn_s_setprio(1);
#pragma unroll
    for (int i = 0; i < 4; i++)
#pragma unroll
      for (int j = 0; j < 4; j++)
        acc[i][j] = __builtin_amdgcn_mfma_f32_16x16x32_bf16(a0[i], b1[j], acc[i][j], 0, 0, 0);
    __builtin_amdgcn_s_setprio(0);
    // read-ahead p4: A11
#pragma unroll
    for (int i = 0; i < 4; i++) a1[i] = *(const bf16x8*)(bc + (1 << 14) + (1 << 13) + abase + (i << 10));
    asm volatile("s_barrier" ::: "memory");

    // ==== phase 4: qm=1,k=1 (b1 reused) ====
    stA(bc, 1, 0, kt2); stB(bc, 0, 1, kt2);
    asm volatile("s_waitcnt vmcnt(5)" ::: "memory");  // tile T+1 fully landed
    asm volatile("s_barrier" ::: "memory");
    asm volatile("s_waitcnt lgkmcnt(0)" ::: "memory");
    __builtin_amdgcn_s_setprio(1);
#pragma unroll
    for (int i = 0; i < 4; i++)
#pragma unroll
      for (int j = 0; j < 4; j++)
        acc[4 + i][j] = __builtin_amdgcn_mfma_f32_16x16x32_bf16(a1[i], b1[j], acc[4 + i][j], 0, 0, 0);
    __builtin_amdgcn_s_setprio(0);
    asm volatile("s_barrier" ::: "memory");
  }

  // drain tail prefetches
  asm volatile("s_waitcnt vmcnt(0)" ::: "memory");

  // epilogue: C/D layout col=lane&15, row=(lane>>4)*4+reg [m89/m91 verified]
  const float beta = scal[1] * beta_scale;
  const int orow0 = rowBase + (wm << 7) + (hi4 << 2);
  const int ocol = colBase + (wn << 6) + fr;
#pragma unroll
  for (int mf = 0; mf < 8; mf++)
#pragma unroll
    for (int j = 0; j < 4; j++)
#pragma unroll
      for (int r = 0; r < 4; r++)
        C[(size_t)(orow0 + mf * 16 + r) * N + (ocol + j * 16)] = acc[mf][j][r] * beta;
}

// ---------- launch ----------

extern "C" void kernel_launch(void* const* d_in, const int* in_sizes, int n_in,
                              void* d_out, int out_size, void* d_ws, size_t ws_size,
                              hipStream_t stream) {
  const float* x = (const float*)d_in[0];   // [4,2048,4096] fp32
  const float* w = (const float*)d_in[1];   // [4096,4096] fp32
  float* out = (float*)d_out;               // [4,2048,4096] fp32

  const int K = 4096;
  const int M = in_sizes[0] / K;  // 8192
  const int N = in_sizes[1] / K;  // 4096
  const int nw = N * K;           // 16777216
  const float inv_nw = 1.0f / (float)nw;

  char* ws = (char*)d_ws;
  float* scal = (float*)ws;                                  // [0]=sum(W), [1]=sum|W-mean|
  __bf16* wbin = (__bf16*)(ws + 256);                        // N*K bf16 = 32 MB
  __bf16* xn = (__bf16*)(ws + 256 + (size_t)nw * 2);         // M*K bf16 = 64 MB

  static int attr_done = 0;
  if (!attr_done) {
    hipFuncSetAttribute((const void*)gemm_kernel,
                        hipFuncAttributeMaxDynamicSharedMemorySize, 2 * LDS_BUF);
    attr_done = 1;
  }

  zero_kernel<<<1, 64, 0, stream>>>(scal);
  wsum_kernel<<<1024, 256, 0, stream>>>(w, scal, nw / 4);
  wbin_kernel<<<1024, 256, 0, stream>>>(w, scal, (unsigned short*)wbin, nw / 4, inv_nw);
  ln_kernel<<<M, 256, 0, stream>>>(x, xn);
  const int nwg = (M >> 8) * (N >> 8);  // 32*16 = 512
  gemm_kernel<<<dim3(nwg), 512, 2 * LDS_BUF, stream>>>(xn, wbin, out, scal, inv_nw, M, N, K);
}